// Round 3
// baseline (798.269 us; speedup 1.0000x reference)
//
#include <hip/hip_runtime.h>
#include <math.h>

#define NB    4096
#define NH    128
#define NKIN  8
#define NKOUT 4
#define NTP   64
#define NL    128
#define BKIN  (NB*NKIN)
#define LOG2E 1.44269504088896340736f

typedef __attribute__((ext_vector_type(8))) short short8;
typedef __attribute__((ext_vector_type(4))) float f32x4;

#if __has_builtin(__builtin_amdgcn_exp2f)
#define EXP2F __builtin_amdgcn_exp2f
#else
#define EXP2F exp2f
#endif

__device__ __forceinline__ short f2bf(float f) {
    union { float f; unsigned u; } v; v.f = f;
    unsigned u = v.u;
    return (short)((u + 0x7fffu + ((u >> 16) & 1u)) >> 16);
}
__device__ __forceinline__ unsigned pkbf2(float a, float b) {
#if __has_builtin(__builtin_amdgcn_cvt_pk_bf16_f32)
    auto p = __builtin_amdgcn_cvt_pk_bf16_f32(a, b);
    unsigned q; __builtin_memcpy(&q, &p, 4); return q;
#else
    union { float f; unsigned u; } x, y; x.f = a; y.f = b;
    unsigned ua = (x.u + 0x7fffu + ((x.u >> 16) & 1u)) >> 16;
    unsigned ub = (y.u + 0x7fffu + ((y.u >> 16) & 1u)) & 0xffff0000u;
    return ua | ub;
#endif
}
// store 4 fp32 as 4 packed bf16 (one ds_write_b64); dst must be 8B-aligned
__device__ __forceinline__ void st4(short* dst, const f32x4& v) {
    uint2 q; q.x = pkbf2(v[0], v[1]); q.y = pkbf2(v[2], v[3]);
    *(uint2*)dst = q;
}

// ---------------- spline: Thomas solve -> UM (midpoint control values) ----
__global__ void spline_um_kernel(const float* __restrict__ pre_x,
                                 const float* __restrict__ fx,
                                 float* __restrict__ UM)
{
    __shared__ float cp[128];
    if (threadIdx.x == 0) {
        float c = 0.f;
        for (int j = 1; j <= 127; ++j) { c = 1.0f/(4.0f - c); cp[j] = c; }
    }
    __syncthreads();
    int col = blockIdx.x*128 + threadIdx.x;
    const float r6 = 6.0f/(0.1f*0.1f);
    const float KK = 0.01f/16.0f;   // hs^2/16
    float y0 = pre_x[(size_t)(NTP-1)*BKIN + col];   // ys[0]
    float y1 = fx[col];                              // ys[1]
    float d = 0.f;
    for (int j = 1; j <= 127; ++j) {
        float y2 = fx[(size_t)j*BKIN + col];         // ys[j+1]
        float r  = r6*(y0 - 2.f*y1 + y2);
        d = (r - d)*cp[j];
        UM[(size_t)j*BKIN + col] = d;
        y0 = y1; y1 = y2;
    }
    float xn  = 0.f;
    float yj1 = fx[(size_t)127*BKIN + col];
    for (int j = 127; j >= 1; --j) {
        float dj = UM[(size_t)j*BKIN + col];
        float x  = dj - cp[j]*xn;                    // M_j
        float yj = fx[(size_t)(j-1)*BKIN + col];
        UM[(size_t)j*BKIN + col] = 0.5f*(yj + yj1) - KK*(x + xn);
        xn = x; yj1 = yj;
    }
    float ys0 = pre_x[(size_t)(NTP-1)*BKIN + col];
    UM[col] = 0.5f*(ys0 + yj1) - KK*xn;
}

// ---------------- prep: W1/W2 as A-operand fragments (bf16, W1 pre-scaled) ----
__global__ void prep_frags(const float* __restrict__ W1, const float* __restrict__ W2,
                           short* __restrict__ w1f, short* __restrict__ w2f)
{
    int tid = threadIdx.x;
    // W1 A-frag: rows = W1 rows (256 = 16 tiles), scaled 2*log2e for exp2-tanh
    for (int idx = tid; idx < 16*4*64*8; idx += 256) {
        int j = idx & 7, lane = (idx >> 3) & 63, kc = (idx >> 9) & 3, t = idx >> 11;
        int row = t*16 + (lane & 15);
        int k   = kc*32 + (lane >> 4)*8 + j;
        w1f[idx] = f2bf(2.0f*LOG2E*W1[row*NH + k]);
    }
    // W2 A-frag: rows ko (4, padded to 16)
    for (int idx = tid; idx < 8*64*8; idx += 256) {
        int j = idx & 7, lane = (idx >> 3) & 63, kc = idx >> 9;
        int m = lane & 15;
        int k = kc*32 + (lane >> 4)*8 + j;
        w2f[idx] = (m < NKOUT) ? f2bf(W2[m*2*NH + k]) : (short)0;
    }
}

// ---------------- fused kernel helpers ----------------
__device__ __forceinline__ void gemmB(const short* bp, const short8 (&A)[3][4], f32x4 (&acc)[3])
{
    #pragma unroll
    for (int kc = 0; kc < 4; ++kc) {
        short8 b = *(const short8*)(bp + kc*32);
        #pragma unroll
        for (int g = 0; g < 3; ++g)
            acc[g] = __builtin_amdgcn_mfma_f32_16x16x32_bf16(A[g][kc], b, acc[g], 0, 0, 0);
    }
}

// gate accs pre-scaled: r,z by -log2e (sig = rcp(1+exp2(a))), n by 2log2e
__device__ __forceinline__ void gateK(const f32x4 (&gi)[3], const f32x4 (&gh)[3],
                                      const f32x4& yin, f32x4& K)
{
    #pragma unroll
    for (int r = 0; r < 4; ++r) {
        float rg = __builtin_amdgcn_rcpf(1.0f + EXP2F(gi[0][r] + gh[0][r]));
        float zg = __builtin_amdgcn_rcpf(1.0f + EXP2F(gi[1][r] + gh[1][r]));
        float tg = 1.0f - 2.0f*__builtin_amdgcn_rcpf(1.0f + EXP2F(gi[2][r] + rg*gh[2][r]));
        K[r] = (1.0f - zg)*(tg - yin[r]);
    }
}

__global__ void __launch_bounds__(512, 2)
fused_kernel(const float* __restrict__ pre_x, const float* __restrict__ pre_y,
             const float* __restrict__ fx,
             const float* __restrict__ W_ih, const float* __restrict__ W_hh,
             const float* __restrict__ b_ih, const float* __restrict__ b_hh,
             const float* __restrict__ W_e,  const float* __restrict__ b_e,
             const float* __restrict__ Wc_ih,const float* __restrict__ Wc_hh,
             const float* __restrict__ bc_ih,const float* __restrict__ bc_hh,
             const float* __restrict__ UM,   const short* __restrict__ w1f,
             const short* __restrict__ w2f,  float* __restrict__ out)
{
    // state buffers: [batch 16][dim], stride 136 shorts (16B-mult, odd*8)
    __shared__ __align__(16) short yT [16*136];
    __shared__ __align__(16) short E0 [16*136];
    __shared__ __align__(16) short E1 [16*136];
    __shared__ __align__(16) short xmT[16*136];
    __shared__ __align__(16) short x1T[16*136];
    __shared__ __align__(16) short UMb[16*40];
    __shared__ __align__(16) short U1b[16*40];
    __shared__ __align__(16) short oT [16*264];

    const int tid  = threadIdx.x;
    const int w    = tid >> 6;
    const int lane = tid & 63;
    const int quad = lane >> 4;
    const int m    = lane & 15;          // A: weight-row within tile; B/D: batch col
    const int hq   = w*16 + quad*4;      // first of this lane's 4 h-rows
    const int b0   = blockIdx.x * 16;
    const f32x4 z4 = {0.f, 0.f, 0.f, 0.f};

    for (int i = tid; i < 16*136; i += 512) yT[i] = 0;
    for (int i = tid; i < 16*40;  i += 512) { UMb[i] = 0; U1b[i] = 0; }

    const float scg[3] = {-LOG2E, -LOG2E, 2.0f*LOG2E};

    // ---- persistent A-frags: ODE cell weights (pre-scaled bf16) ----
    short8 Ahh[3][4], Aih[3][4];
    #pragma unroll
    for (int g = 0; g < 3; ++g)
        #pragma unroll
        for (int c = 0; c < 4; ++c) {
            const float* ph = Wc_hh + (size_t)(g*NH + w*16 + m)*NH + c*32 + quad*8;
            const float* pi = Wc_ih + (size_t)(g*NH + w*16 + m)*NH + c*32 + quad*8;
            short8 fh, fi;
            #pragma unroll
            for (int j = 0; j < 8; ++j) { fh[j] = f2bf(scg[g]*ph[j]); fi[j] = f2bf(scg[g]*pi[j]); }
            Ahh[g][c] = fh; Aih[g][c] = fi;
        }
    short8 Aexp;
    #pragma unroll
    for (int j = 0; j < 8; ++j) {
        int k = quad*8 + j;
        Aexp[j] = (k < NKIN) ? f2bf(2.0f*LOG2E*W_e[(w*16 + m)*NKIN + k]) : (short)0;
    }
    // bias seed vectors (per lane's 4 h-rows)
    f32x4 brz4, bzz4, bgn4, bin4, be4;
    #pragma unroll
    for (int r = 0; r < 4; ++r) {
        int h = hq + r;
        brz4[r] = -LOG2E*(bc_ih[h]      + bc_hh[h]);
        bzz4[r] = -LOG2E*(bc_ih[NH + h] + bc_hh[NH + h]);
        bgn4[r] = 2.0f*LOG2E*bc_hh[2*NH + h];
        bin4[r] = 2.0f*LOG2E*bc_ih[2*NH + h];
        be4[r]  = 2.0f*LOG2E*b_e[h];
    }

    f32x4 y = z4;

    // ================= encoder GRU (64 steps) =================
    {
        short8 Ehh[3][4];
        #pragma unroll
        for (int g = 0; g < 3; ++g)
            #pragma unroll
            for (int c = 0; c < 4; ++c) {
                const float* ph = W_hh + (size_t)(g*NH + w*16 + m)*NH + c*32 + quad*8;
                short8 fh;
                #pragma unroll
                for (int j = 0; j < 8; ++j) fh[j] = f2bf(scg[g]*ph[j]);
                Ehh[g][c] = fh;
            }
        short8 Eih[3];
        #pragma unroll
        for (int g = 0; g < 3; ++g) {
            short8 f1;
            #pragma unroll
            for (int j = 0; j < 8; ++j) {
                int k = quad*8 + j;
                f1[j] = (k < 12) ? f2bf(scg[g]*W_ih[(size_t)(g*NH + w*16 + m)*12 + k]) : (short)0;
            }
            Eih[g] = f1;
        }
        f32x4 erz4, ezz4, egn4, ein4;
        #pragma unroll
        for (int r = 0; r < 4; ++r) {
            int h = hq + r;
            erz4[r] = -LOG2E*(b_ih[h]      + b_hh[h]);
            ezz4[r] = -LOG2E*(b_ih[NH + h] + b_hh[NH + h]);
            egn4[r] = 2.0f*LOG2E*b_hh[2*NH + h];
            ein4[r] = 2.0f*LOG2E*b_ih[2*NH + h];
        }
        const int eb = tid / 12, ek = tid - eb*12;
        float encv = 0.f;
        if (tid < 192)
            encv = (ek < NKIN) ? pre_x[((size_t)0*NB + b0 + eb)*NKIN + ek]
                               : pre_y[((size_t)0*NB + b0 + eb)*NKOUT + (ek - NKIN)];
        __syncthreads();   // zeros visible
        for (int t = 0; t < NTP; ++t) {
            if (tid < 192) {
                UMb[eb*40 + ek] = f2bf(encv);
                if (t + 1 < NTP)
                    encv = (ek < NKIN) ? pre_x[((size_t)(t+1)*NB + b0 + eb)*NKIN + ek]
                                       : pre_y[((size_t)(t+1)*NB + b0 + eb)*NKOUT + (ek - NKIN)];
            }
            __syncthreads();
            f32x4 gi[3] = {z4, z4, ein4};
            {
                short8 b = *(const short8*)(UMb + m*40 + quad*8);
                #pragma unroll
                for (int g = 0; g < 3; ++g)
                    gi[g] = __builtin_amdgcn_mfma_f32_16x16x32_bf16(Eih[g], b, gi[g], 0, 0, 0);
            }
            f32x4 gh[3] = {erz4, ezz4, egn4};
            gemmB(yT + m*136 + quad*8, Ehh, gh);
            f32x4 K;
            gateK(gi, gh, y, K);
            #pragma unroll
            for (int r = 0; r < 4; ++r) y[r] += K[r];
            __syncthreads();
            st4(yT + m*136 + hq, y);
        }
    }

    // ================= RK4 prologue =================
    if (tid < 64) UMb[(tid >> 2)*40 + 8 + (tid & 3)] = 0;   // re-zero enc cols 8..11
    const int sb = tid >> 3, sk = tid & 7;
    const size_t scol = (size_t)(b0 + sb)*NKIN + sk;
    if (tid < 128) UMb[sb*40 + sk] = f2bf(pre_x[(size_t)(NTP-1)*BKIN + scol]);
    __syncthreads();
    {   // x0 = tanh-expand(u0)
        short8 b = *(const short8*)(UMb + m*40 + quad*8);
        f32x4 c0 = be4;
        c0 = __builtin_amdgcn_mfma_f32_16x16x32_bf16(Aexp, b, c0, 0, 0, 0);
        f32x4 xv;
        #pragma unroll
        for (int r = 0; r < 4; ++r)
            xv[r] = 1.0f - 2.0f*__builtin_amdgcn_rcpf(1.0f + EXP2F(c0[r]));
        st4(xmT + m*136 + hq, xv);
    }
    __syncthreads();
    f32x4 gi0[3] = {z4, z4, bin4};
    gemmB(xmT + m*136 + quad*8, Aih, gi0);
    if (tid < 128) { UMb[sb*40 + sk] = f2bf(UM[scol]); U1b[sb*40 + sk] = f2bf(fx[scol]); }
    __syncthreads();
    {   // expand for st=0
        short8 bm = *(const short8*)(UMb + m*40 + quad*8);
        short8 b1 = *(const short8*)(U1b + m*40 + quad*8);
        f32x4 cm = be4, c1 = be4;
        cm = __builtin_amdgcn_mfma_f32_16x16x32_bf16(Aexp, bm, cm, 0, 0, 0);
        c1 = __builtin_amdgcn_mfma_f32_16x16x32_bf16(Aexp, b1, c1, 0, 0, 0);
        f32x4 xm, x1;
        #pragma unroll
        for (int r = 0; r < 4; ++r) {
            xm[r] = 1.0f - 2.0f*__builtin_amdgcn_rcpf(1.0f + EXP2F(cm[r]));
            x1[r] = 1.0f - 2.0f*__builtin_amdgcn_rcpf(1.0f + EXP2F(c1[r]));
        }
        st4(xmT + m*136 + hq, xm);
        st4(x1T + m*136 + hq, x1);
    }
    __syncthreads();
    f32x4 gim[3] = {z4, z4, bin4}, gi1[3] = {z4, z4, bin4};
    gemmB(xmT + m*136 + quad*8, Aih, gim);
    gemmB(x1T + m*136 + quad*8, Aih, gi1);
    float fxv = 0.f, umv = 0.f;
    if (tid < 128) { fxv = fx[BKIN + scol]; umv = UM[BKIN + scol]; }   // st=1

    // ================= RK4 loop: 5 barriers/step =================
    for (int st = 0; st < NL; ++st) {
        // ---- k1 ----
        f32x4 gh[3] = {brz4, bzz4, bgn4};
        gemmB(yT + m*136 + quad*8, Ahh, gh);
        f32x4 K, Ks, ye;
        gateK(gi0, gh, y, K);
        #pragma unroll
        for (int r = 0; r < 4; ++r) { Ks[r] = K[r]; ye[r] = y[r] + 0.5f*K[r]; }
        st4(E0 + m*136 + hq, ye);
        __syncthreads();                                        // B1
        // ---- k2 ----
        gh[0] = brz4; gh[1] = bzz4; gh[2] = bgn4;
        gemmB(E0 + m*136 + quad*8, Ahh, gh);
        gateK(gim, gh, ye, K);
        #pragma unroll
        for (int r = 0; r < 4; ++r) { Ks[r] += 2.f*K[r]; ye[r] = y[r] + 0.5f*K[r]; }
        st4(E1 + m*136 + hq, ye);
        __syncthreads();                                        // B2
        // ---- k3 ----
        gh[0] = brz4; gh[1] = bzz4; gh[2] = bgn4;
        gemmB(E1 + m*136 + quad*8, Ahh, gh);
        gateK(gim, gh, ye, K);
        #pragma unroll
        for (int r = 0; r < 4; ++r) { Ks[r] += 2.f*K[r]; ye[r] = y[r] + K[r]; }
        st4(E0 + m*136 + hq, ye);
        __syncthreads();                                        // B3
        // ---- k4 + y update + staging(st+1) + W1-frag prefetch ----
        gh[0] = brz4; gh[1] = bzz4; gh[2] = bgn4;
        gemmB(E0 + m*136 + quad*8, Ahh, gh);
        gateK(gi1, gh, ye, K);
        #pragma unroll
        for (int r = 0; r < 4; ++r) y[r] += (1.0f/6.0f)*(Ks[r] + K[r]);
        st4(yT + m*136 + hq, y);
        if (tid < 128) { UMb[sb*40 + sk] = f2bf(umv); U1b[sb*40 + sk] = f2bf(fxv); }
        short8 a1f[2][4];
        #pragma unroll
        for (int kc = 0; kc < 4; ++kc) {
            a1f[0][kc] = *(const short8*)(w1f + (size_t)((w*4      + kc)*64 + lane)*8);
            a1f[1][kc] = *(const short8*)(w1f + (size_t)(((w+8)*4 + kc)*64 + lane)*8);
        }
        __syncthreads();                                        // B4
        // ---- head1 + expand(st+1) + prefetch(st+2) + W2-frag prefetch ----
        {
            short8 bm = *(const short8*)(UMb + m*40 + quad*8);
            short8 b1 = *(const short8*)(U1b + m*40 + quad*8);
            f32x4 cm = be4, c1 = be4;
            cm = __builtin_amdgcn_mfma_f32_16x16x32_bf16(Aexp, bm, cm, 0, 0, 0);
            c1 = __builtin_amdgcn_mfma_f32_16x16x32_bf16(Aexp, b1, c1, 0, 0, 0);
            f32x4 xm, x1;
            #pragma unroll
            for (int r = 0; r < 4; ++r) {
                xm[r] = 1.0f - 2.0f*__builtin_amdgcn_rcpf(1.0f + EXP2F(cm[r]));
                x1[r] = 1.0f - 2.0f*__builtin_amdgcn_rcpf(1.0f + EXP2F(c1[r]));
            }
            st4(xmT + m*136 + hq, xm);
            st4(x1T + m*136 + hq, x1);
        }
        {
            f32x4 o0 = z4, o1 = z4;
            #pragma unroll
            for (int kc = 0; kc < 4; ++kc) {
                short8 b = *(const short8*)(yT + m*136 + quad*8 + kc*32);
                o0 = __builtin_amdgcn_mfma_f32_16x16x32_bf16(a1f[0][kc], b, o0, 0, 0, 0);
                o1 = __builtin_amdgcn_mfma_f32_16x16x32_bf16(a1f[1][kc], b, o1, 0, 0, 0);
            }
            f32x4 t0, t1;
            #pragma unroll
            for (int r = 0; r < 4; ++r) {
                t0[r] = 1.0f - 2.0f*__builtin_amdgcn_rcpf(1.0f + EXP2F(o0[r]));
                t1[r] = 1.0f - 2.0f*__builtin_amdgcn_rcpf(1.0f + EXP2F(o1[r]));
            }
            st4(oT + m*264 + w*16     + quad*4, t0);
            st4(oT + m*264 + (w+8)*16 + quad*4, t1);
        }
        if (tid < 128) {
            if (st + 2 < NL) { fxv = fx[(size_t)(st+2)*BKIN + scol]; umv = UM[(size_t)(st+2)*BKIN + scol]; }
            else             { fxv = 0.f; umv = 0.f; }
        }
        short8 a2f[8];
        if (w == (st & 7)) {
            #pragma unroll
            for (int kc = 0; kc < 8; ++kc)
                a2f[kc] = *(const short8*)(w2f + (size_t)(kc*64 + lane)*8);
        }
        __syncthreads();                                        // B5
        // ---- stage2 (rotating wave) + gim/gi1 for st+1 (no trailing barrier) ----
        if (w == (st & 7)) {
            f32x4 oc = z4;
            #pragma unroll
            for (int kc = 0; kc < 8; ++kc) {
                short8 b = *(const short8*)(oT + m*264 + kc*32 + quad*8);
                oc = __builtin_amdgcn_mfma_f32_16x16x32_bf16(a2f[kc], b, oc, 0, 0, 0);
            }
            if (quad == 0)
                *(f32x4*)(out + ((size_t)st*NB + b0 + m)*NKOUT) = oc;
        }
        gi0[0] = gi1[0]; gi0[1] = gi1[1]; gi0[2] = gi1[2];
        gim[0] = z4; gim[1] = z4; gim[2] = bin4;
        gi1[0] = z4; gi1[1] = z4; gi1[2] = bin4;
        gemmB(xmT + m*136 + quad*8, Aih, gim);
        gemmB(x1T + m*136 + quad*8, Aih, gi1);
    }
}

extern "C" void kernel_launch(void* const* d_in, const int* in_sizes, int n_in,
                              void* d_out, int out_size, void* d_ws, size_t ws_size,
                              hipStream_t stream)
{
    const float* pre_x = (const float*)d_in[0];
    const float* pre_y = (const float*)d_in[1];
    const float* fx    = (const float*)d_in[2];
    const float* W_ih  = (const float*)d_in[3];
    const float* W_hh  = (const float*)d_in[4];
    const float* b_ih  = (const float*)d_in[5];
    const float* b_hh  = (const float*)d_in[6];
    const float* W_e   = (const float*)d_in[7];
    const float* b_e   = (const float*)d_in[8];
    const float* Wc_ih = (const float*)d_in[9];
    const float* Wc_hh = (const float*)d_in[10];
    const float* bc_ih = (const float*)d_in[11];
    const float* bc_hh = (const float*)d_in[12];
    const float* W1    = (const float*)d_in[13];
    const float* W2    = (const float*)d_in[14];
    float* out = (float*)d_out;

    float* UM  = (float*)d_ws;                                  // 128*4096*8 fp32 = 16.78 MB
    short* w1f = (short*)((char*)d_ws + (size_t)NL*NB*NKIN*4);  // 32768 shorts
    short* w2f = w1f + 16*4*64*8;                               // 4096 shorts

    prep_frags<<<dim3(1), dim3(256), 0, stream>>>(W1, W2, w1f, w2f);
    spline_um_kernel<<<dim3((NB*NKIN)/128), dim3(128), 0, stream>>>(pre_x, fx, UM);
    fused_kernel<<<dim3(NB/16), dim3(512), 0, stream>>>(
        pre_x, pre_y, fx, W_ih, W_hh, b_ih, b_hh, W_e, b_e,
        Wc_ih, Wc_hh, bc_ih, bc_hh, UM, w1f, w2f, out);
}